// Round 4
// baseline (127.829 us; speedup 1.0000x reference)
//
#include <hip/hip_runtime.h>
#include <math.h>

#define N      512
#define RNUM   4
#define BNUM   2
#define NSLICE (RNUM * BNUM)
#define TILE   128               // (a,b) tile 128x128; 512 threads x (8a x 4b)
#define CT     32                // c-chunk per LDS stage
#define LSTRF  132               // f32 row stride (528 B) — writes: 64 consec dwords = 2-way, free
#define CSPLIT 16                // c-split -> 2048 main blocks
#define NCOLB  8                 // colsum-role blocks (1 per slice, 512 threads)
#define SCALE  0.0625f           // (1/2 relu-split) * (1/8 weight/(R*B))

typedef _Float16 half2_t __attribute__((ext_vector_type(2)));

__device__ __forceinline__ half2_t u2h(unsigned int u) {
  return __builtin_bit_cast(half2_t, u);
}

__device__ __forceinline__ float sigmoidf_(float x) {
  return 1.0f / (1.0f + __expf(-x));
}

__device__ __forceinline__ unsigned packh2(float a, float b) {
  half2_t h = {(_Float16)a, (_Float16)b};
  return __builtin_bit_cast(unsigned, h);
}

__global__ void zero_out_kernel(float* out) { out[0] = 0.0f; }

// prep: one thread per (b,i,4xj): 64B contiguous logits load (4x float4),
// 16 sigmoids, per-plane 8B packed store (uint2 of 4 f16). P stays f16 (4MB).
__global__ __launch_bounds__(256) void prep_f16_kernel(const float* __restrict__ logits,
                                                       const int* __restrict__ masks,
                                                       _Float16* __restrict__ P,
                                                       float* __restrict__ out) {
  if (blockIdx.x == 0 && threadIdx.x == 0) out[0] = 0.0f;
  int t = blockIdx.x * 256 + threadIdx.x;      // 0 .. B*N*N/4 - 1
  int b = t >> 16;                              // / (N*N/4)
  int rem4 = t & (N * N / 4 - 1);
  int i = rem4 >> 7;                            // row
  int j4 = rem4 & 127;                          // j-group (j = 4*j4)
  const float4* Lp = ((const float4*)logits) + ((size_t)(b * N + i) * N + 4 * j4);
  float4 l0 = Lp[0], l1 = Lp[1], l2 = Lp[2], l3 = Lp[3];
  int4 mj = *(const int4*)(masks + b * N + 4 * j4);
  float mi = (masks[b * N + i] > 0) ? 1.0f : 0.0f;
  float m0 = mi * ((mj.x > 0) ? 1.0f : 0.0f);
  float m1 = mi * ((mj.y > 0) ? 1.0f : 0.0f);
  float m2 = mi * ((mj.z > 0) ? 1.0f : 0.0f);
  float m3 = mi * ((mj.w > 0) ? 1.0f : 0.0f);
  size_t off = (size_t)i * N + 4 * j4;
  _Float16* Pb = P + (size_t)b * RNUM * N * N + off;
  {
    uint2 v = {packh2(m0 * sigmoidf_(l0.x), m1 * sigmoidf_(l1.x)),
               packh2(m2 * sigmoidf_(l2.x), m3 * sigmoidf_(l3.x))};
    *(uint2*)(Pb + 0 * (size_t)N * N) = v;
  }
  {
    uint2 v = {packh2(m0 * sigmoidf_(l0.y), m1 * sigmoidf_(l1.y)),
               packh2(m2 * sigmoidf_(l2.y), m3 * sigmoidf_(l3.y))};
    *(uint2*)(Pb + 1 * (size_t)N * N) = v;
  }
  {
    uint2 v = {packh2(m0 * sigmoidf_(l0.z), m1 * sigmoidf_(l1.z)),
               packh2(m2 * sigmoidf_(l2.z), m3 * sigmoidf_(l3.z))};
    *(uint2*)(Pb + 2 * (size_t)N * N) = v;
  }
  {
    uint2 v = {packh2(m0 * sigmoidf_(l0.w), m1 * sigmoidf_(l1.w)),
               packh2(m2 * sigmoidf_(l2.w), m3 * sigmoidf_(l3.w))};
    *(uint2*)(Pb + 3 * (size_t)N * N) = v;
  }
}

// R12 journal: 4 rounds (R8-R11) pinned at ~60us across 3 different packed-f16
// codegens; VALUBusy*dur = 42us each time = inst_count x 4 cyc EXACTLY =>
// VOP3P (v_pk_fma_f16 / v_dot2 / v_pk_add) issues at 4 cyc/wave64 on gfx950
// (SIMD-16 rate), while v_fma_f32 is 2 cyc (m07). Packed f16 gains nothing.
// => switch inner math to f32: fma(2cyc) + add-with-|abs|-modifier(2cyc)
//    = 4 cyc/elem; device essential = 27.3us (vs 42.7 packed floor).
//  * 512-thread blocks, 8a x 4b per thread, CT=32, f32 LDS tiles (33.9KB).
//  * P stays f16: staging converts f16->f32 (one-time ~24 cvt/thread);
//    rab loaded packed f16 (8x dwordx2), unpacked once to 32 f32 regs.
//  * __launch_bounds__(512,8): 64-VGPR cap -> 4 blocks/CU = 32 waves/CU
//    (100% occupancy). Budget: rab 32 + acc 8 + av 8 + bv 4 + addr ~ 62.
//    FALSIFIER: VGPR=64 + regression => spill => back off to (512,4).
__global__ __launch_bounds__(512, 8) void work_f16_kernel(const _Float16* __restrict__ P,
                                                          float* __restrict__ out) {
  __shared__ __align__(16) float tA[CT][LSTRF];
  __shared__ __align__(16) float tB[CT][LSTRF];
  __shared__ float wsum[8];

  const int tid = threadIdx.x;
  const int bid = blockIdx.x;

  if (bid < NCOLB) {
    // ---- colsum role: Sum_c csum_c*(N-csum_c), one block per slice ----
    const int s = bid;
    const int c = tid;                      // 0..511
    const _Float16* col = P + (size_t)s * N * N + c;
    float sum = 0.0f;
#pragma unroll 16
    for (int a = 0; a < N; ++a) sum += (float)col[(size_t)a * N];
    float v = sum * ((float)N - sum);
    for (int off = 32; off > 0; off >>= 1) v += __shfl_down(v, off, 64);
    const int wid = tid >> 6;
    if ((tid & 63) == 0) wsum[wid] = v;
    __syncthreads();
    if (tid == 0) {
      float t = 0.0f;
#pragma unroll
      for (int w = 0; w < 8; ++w) t += wsum[w];
      atomicAdd(out, t * SCALE);
    }
    return;
  }

  // ---- main role: Sum |rab - a_c*b_c| in f32 ----
  const int m  = bid - NCOLB;
  const int bt = m & 3;
  const int at = (m >> 2) & 3;
  const int s  = (m >> 4) & 7;
  const int cz = m >> 7;                    // 0..CSPLIT-1
  const int a0 = at * TILE;
  const int b0 = bt * TILE;
  const int c0 = cz * CT;                   // one CT-chunk per block

  const int ta  = tid & 15;   // a cols: a0 + ta*8 + {0..7}
  const int tbg = tid >> 5;   // hmm placeholder (overwritten below)

  const int tbgq = tid >> 4;  // b cols: b0 + tbgq*4 + {0..3}  (0..31)
  (void)tbg;

  const _Float16* Ph = P + (size_t)s * N * N;

  // staging: thread r=tid&127, oct=tid>>7 stages cols [oct*8,oct*8+8) of row r
  // for BOTH tiles, converting f16->f32. ds_writes: fixed (oct,k), lanes are
  // 64 consecutive r -> consecutive dwords -> 2-way bank alias (free).
  {
    const int r   = tid & 127;
    const int oct = tid >> 7;               // 0..3
    const _Float16* sa = Ph + (size_t)(a0 + r) * N + c0 + oct * 8;
    const _Float16* sb = Ph + (size_t)(b0 + r) * N + c0 + oct * 8;
    uint4 qa = *(const uint4*)sa;
    uint4 qb = *(const uint4*)sb;
    unsigned wa[4] = {qa.x, qa.y, qa.z, qa.w};
    unsigned wb[4] = {qb.x, qb.y, qb.z, qb.w};
#pragma unroll
    for (int k = 0; k < 4; ++k) {
      half2_t ha = u2h(wa[k]);
      half2_t hb = u2h(wb[k]);
      tA[oct * 8 + 2 * k    ][r] = (float)ha.x;
      tA[oct * 8 + 2 * k + 1][r] = (float)ha.y;
      tB[oct * 8 + 2 * k    ][r] = (float)hb.x;
      tB[oct * 8 + 2 * k + 1][r] = (float)hb.y;
    }
  }

  // rab tile: per x one dwordx2 (4 f16), unpack once to f32.
  float rabf[8][4];
#pragma unroll
  for (int x = 0; x < 8; ++x) {
    int ga = a0 + ta * 8 + x;
    uint2 q = *(const uint2*)(Ph + (size_t)ga * N + b0 + tbgq * 4);
    half2_t h0 = u2h(q.x);
    half2_t h1 = u2h(q.y);
    rabf[x][0] = (float)h0.x; rabf[x][1] = (float)h0.y;
    rabf[x][2] = (float)h1.x; rabf[x][3] = (float)h1.y;
  }

  float acc[8];
#pragma unroll
  for (int x = 0; x < 8; ++x) acc[x] = 0.0f;

  __syncthreads();

#pragma unroll 2
  for (int c = 0; c < CT; ++c) {
    float4 a0v = *(const float4*)&tA[c][ta * 8];
    float4 a1v = *(const float4*)&tA[c][ta * 8 + 4];
    float4 b0v = *(const float4*)&tB[c][tbgq * 4];
    float av[8] = {a0v.x, a0v.y, a0v.z, a0v.w, a1v.x, a1v.y, a1v.z, a1v.w};
    float bv[4] = {b0v.x, b0v.y, b0v.z, b0v.w};
#pragma unroll
    for (int x = 0; x < 8; ++x) {
#pragma unroll
      for (int y = 0; y < 4; ++y)
        acc[x] += fabsf(fmaf(-av[x], bv[y], rabf[x][y]));   // v_fma + v_add(|.|)
    }
  }

  float tsum = 0.0f;
#pragma unroll
  for (int x = 0; x < 8; ++x) tsum += acc[x];

  for (int off = 32; off > 0; off >>= 1) tsum += __shfl_down(tsum, off, 64);

  const int wid = tid >> 6;
  if ((tid & 63) == 0) wsum[wid] = tsum;
  __syncthreads();
  if (tid == 0) {
    float t = 0.0f;
#pragma unroll
    for (int w = 0; w < 8; ++w) t += wsum[w];
    atomicAdd(out, t * SCALE);
  }
}

// ---------------- f32 fallback (no workspace): R4 structure ----------------
#define FCT    64
#define FSTR   132
#define FCSPL  4
#define FNCOLB 16

__global__ __launch_bounds__(256, 2) void work_f32_fallback(const float* __restrict__ logits,
                                                            const int* __restrict__ masks,
                                                            float* __restrict__ out) {
  __shared__ __align__(16) float tA[FCT][FSTR];
  __shared__ __align__(16) float tB[FCT][FSTR];
  __shared__ float wsum[4];

  const int tid = threadIdx.x;
  const int bid = blockIdx.x;

  if (bid < FNCOLB) {
    const int s    = bid >> 1;
    const int half = bid & 1;
    const int c    = half * 256 + tid;
    const int bb   = s >> 2;
    const int r    = s & 3;
    const int* mrow = masks + bb * N;
    float mc = (mrow[c] > 0) ? 1.0f : 0.0f;
    float sum = 0.0f;
#pragma unroll 4
    for (int a = 0; a < N; ++a) {
      float ma = (mrow[a] > 0) ? 1.0f : 0.0f;
      size_t idx = ((size_t)(bb * N + a) * N + c) * RNUM + r;
      sum += sigmoidf_(logits[idx]) * ma * mc;
    }
    float v = sum * ((float)N - sum);
    for (int off = 32; off > 0; off >>= 1) v += __shfl_down(v, off, 64);
    const int wid = tid >> 6;
    if ((tid & 63) == 0) wsum[wid] = v;
    __syncthreads();
    if (tid == 0)
      atomicAdd(out, (wsum[0] + wsum[1] + wsum[2] + wsum[3]) * SCALE);
    return;
  }

  const int m  = bid - FNCOLB;
  const int bt = m & 3;
  const int at = (m >> 2) & 3;
  const int s  = (m >> 4) & 7;
  const int cz = m >> 7;
  const int a0 = at * TILE;
  const int b0 = bt * TILE;
  const int bb = s >> 2;
  const int r  = s & 3;
  const int cbeg = cz * (N / FCSPL);
  const int cend = cbeg + (N / FCSPL);

  const int ta = tid & 15;
  const int tb = tid >> 4;
  const int* mrow = masks + bb * N;

  float rab[8][8];
#pragma unroll
  for (int x = 0; x < 8; ++x) {
    int ra = a0 + ((x >> 2) << 6) + ta * 4 + (x & 3);
    float ma = (mrow[ra] > 0) ? 1.0f : 0.0f;
#pragma unroll
    for (int y = 0; y < 8; ++y) {
      int cb = b0 + ((y >> 2) << 6) + tb * 4 + (y & 3);
      float mb = (mrow[cb] > 0) ? 1.0f : 0.0f;
      size_t idx = ((size_t)(bb * N + ra) * N + cb) * RNUM + r;
      rab[x][y] = sigmoidf_(logits[idx]) * ma * mb;
    }
  }

  float acc[8][2];
#pragma unroll
  for (int x = 0; x < 8; ++x) { acc[x][0] = 0.0f; acc[x][1] = 0.0f; }

  for (int c0 = cbeg; c0 < cend; c0 += FCT) {
    __syncthreads();
#pragma unroll
    for (int it = 0; it < 32; ++it) {
      int e = it * 256 + tid;
      int c = e & 63;
      int i = e >> 6;
      int pc = ((((i >> 2) ^ ((c >> 2) & 31)) & 31) << 2) | (i & 3);
      float mc = (mrow[c0 + c] > 0) ? 1.0f : 0.0f;
      {
        float mi = (mrow[a0 + i] > 0) ? 1.0f : 0.0f;
        size_t idx = ((size_t)(bb * N + a0 + i) * N + (c0 + c)) * RNUM + r;
        tA[c][pc] = sigmoidf_(logits[idx]) * mi * mc;
      }
      {
        float mi = (mrow[b0 + i] > 0) ? 1.0f : 0.0f;
        size_t idx = ((size_t)(bb * N + b0 + i) * N + (c0 + c)) * RNUM + r;
        tB[c][pc] = sigmoidf_(logits[idx]) * mi * mc;
      }
    }
    __syncthreads();

#pragma unroll 2
    for (int cg = 0; cg < FCT / 4; ++cg) {
      const float* pa = &tA[cg * 4][((ta ^ cg) & 31) << 2];
      const float* pb = &tB[cg * 4][((tb ^ cg) & 31) << 2];
#pragma unroll
      for (int dc = 0; dc < 4; ++dc) {
        float4 a0v = *(const float4*)(pa + dc * FSTR);
        float4 a1v = *(const float4*)(pa + dc * FSTR + 64);
        float4 b0v = *(const float4*)(pb + dc * FSTR);
        float4 b1v = *(const float4*)(pb + dc * FSTR + 64);
        float avv[8] = {a0v.x, a0v.y, a0v.z, a0v.w, a1v.x, a1v.y, a1v.z, a1v.w};
        float bvv[8] = {b0v.x, b0v.y, b0v.z, b0v.w, b1v.x, b1v.y, b1v.z, b1v.w};
#pragma unroll
        for (int x = 0; x < 8; ++x) {
#pragma unroll
          for (int y = 0; y < 4; ++y)
            acc[x][0] += fabsf(fmaf(-avv[x], bvv[y], rab[x][y]));
#pragma unroll
          for (int y = 4; y < 8; ++y)
            acc[x][1] += fabsf(fmaf(-avv[x], bvv[y], rab[x][y]));
        }
      }
    }
  }

  float tsum = 0.0f;
#pragma unroll
  for (int x = 0; x < 8; ++x) tsum += acc[x][0] + acc[x][1];
  for (int off = 32; off > 0; off >>= 1) tsum += __shfl_down(tsum, off, 64);
  const int wid = tid >> 6;
  if ((tid & 63) == 0) wsum[wid] = tsum;
  __syncthreads();
  if (tid == 0)
    atomicAdd(out, (wsum[0] + wsum[1] + wsum[2] + wsum[3]) * SCALE);
}

extern "C" void kernel_launch(void* const* d_in, const int* in_sizes, int n_in,
                              void* d_out, int out_size, void* d_ws, size_t ws_size,
                              hipStream_t stream) {
  const float* logits = (const float*)d_in[0];
  const int*   masks  = (const int*)d_in[1];
  float*       out    = (float*)d_out;

  const size_t P_BYTES = (size_t)NSLICE * N * N * sizeof(_Float16);  // 4 MB

  if (ws_size >= P_BYTES) {
    _Float16* P = (_Float16*)d_ws;
    prep_f16_kernel<<<(BNUM * N * N / 4) / 256, 256, 0, stream>>>(logits, masks, P, out);
    const int nblocks = NCOLB + 4 * 4 * NSLICE * CSPLIT;  // 8 + 2048
    work_f16_kernel<<<nblocks, 512, 0, stream>>>(P, out);
  } else {
    zero_out_kernel<<<1, 1, 0, stream>>>(out);
    const int nblocks = FNCOLB + 4 * 4 * NSLICE * FCSPL;  // 16 + 512
    work_f32_fallback<<<nblocks, 256, 0, stream>>>(logits, masks, out);
  }
}